// Round 10
// baseline (177.723 us; speedup 1.0000x reference)
//
#include <hip/hip_runtime.h>
#include <hip/hip_bf16.h>

// Fused causal self-attention (GQA) for MI355X/gfx950.
// Shapes: B=2, T=2048, C=1024, H=16, Hkv=4, D=64.
// Round 10: attn occupancy fix — 8-wave blocks with intra-block kv-split
// (group 0 = waves 0-3: kv [0,ceil(nt/2)); group 1 = waves 4-7: rest), each
// group own double-buffered K/V LDS (80 KB -> 2 blocks/CU = 16 waves/CU,
// 2x R9), local (o,m,l) merge via LDS overlay. VALU cuts: LOG2E folded into
// Q scale (exp2-domain softmax), P->bf16 via v_cvt_pk_bf16_f32.

typedef __attribute__((ext_vector_type(8))) short s16x8;   // 8 x bf16 raw
typedef __attribute__((ext_vector_type(4))) float f32x4;
typedef __attribute__((ext_vector_type(4))) unsigned short u16x4;

#define LOG2E 1.44269504088896340736f

__device__ __forceinline__ float bf2f(unsigned short u) {
  unsigned int i = ((unsigned int)u) << 16;
  return __builtin_bit_cast(float, i);
}
__device__ __forceinline__ unsigned short f2bf(float f) {
  unsigned int i = __builtin_bit_cast(unsigned int, f);
  i += 0x7fffu + ((i >> 16) & 1u);   // RNE
  return (unsigned short)(i >> 16);
}
__device__ __forceinline__ unsigned int cvtpk(float lo, float hi) {
  unsigned int r;                    // low half <- lo, high half <- hi (T12)
  asm("v_cvt_pk_bf16_f32 %0, %1, %2" : "=v"(r) : "v"(lo), "v"(hi));
  return r;
}

__device__ __forceinline__ void async16(const void* g, void* l) {
  __builtin_amdgcn_global_load_lds(
      (const __attribute__((address_space(1))) void*)g,
      (__attribute__((address_space(3))) void*)l, 16, 0, 0);
}

// ---------------- prep kernels ----------------

__global__ void conv_f32_to_bf16(const float* __restrict__ in,
                                 unsigned short* __restrict__ out, int n) {
  int i = (blockIdx.x * blockDim.x + threadIdx.x) * 4;
  if (i + 3 < n) {
    float4 v = *(const float4*)(in + i);
    u16x4 o = { f2bf(v.x), f2bf(v.y), f2bf(v.z), f2bf(v.w) };
    *(u16x4*)(out + i) = o;
  }
}

// W [K][N] fp32 -> Wt [N][K] bf16
__global__ void transpose_conv(const float* __restrict__ W,
                               unsigned short* __restrict__ Wt, int K, int N) {
  __shared__ float tile[32][33];
  int n0 = blockIdx.x * 32, k0 = blockIdx.y * 32;
  int tx = threadIdx.x, ty = threadIdx.y;
  for (int i = ty; i < 32; i += 8)
    tile[i][tx] = W[(size_t)(k0 + i) * N + n0 + tx];
  __syncthreads();
  for (int i = ty; i < 32; i += 8)
    Wt[(size_t)(n0 + i) * K + k0 + tx] = f2bf(tile[tx][i]);
}

// RoPE on packed QKV [4096][1536]: heads 0..15 = Q (scaled 0.125*log2e ->
// softmax in exp2 domain), heads 16..19 = K at col offset 1024.
__global__ void rope_qk(unsigned short* __restrict__ QKV,
                        const float* __restrict__ cosb,
                        const float* __restrict__ sinb) {
  int idx = blockIdx.x * blockDim.x + threadIdx.x;
  int d = idx & 31;
  int hh = (idx >> 5) % 20;
  int row = idx / (32 * 20);
  int t = row & 2047;
  size_t base;
  float mul;
  if (hh < 16) { base = (size_t)row * 1536 + hh * 64 + d;   mul = 0.125f * LOG2E; }
  else         { base = (size_t)row * 1536 + 1024 + (hh - 16) * 64 + d; mul = 1.0f; }
  float x1 = bf2f(QKV[base]), x2 = bf2f(QKV[base + 32]);
  float c = cosb[t * 32 + d], s = sinb[t * 32 + d];
  QKV[base]      = f2bf((x1 * c + x2 * s) * mul);
  QKV[base + 32] = f2bf((-x1 * s + x2 * c) * mul);
}

// ---------------- GEMM: C[M,N] = A[M,K] * Bt[N,K]^T ----------------
// 128x64 tile, BK=64, 4 waves (2x2), wave = 64x32 via 4x2x2 16x16x32 MFMA.
__global__ __launch_bounds__(256) void gemm_bt(
    const unsigned short* __restrict__ A, const unsigned short* __restrict__ Bt,
    void* __restrict__ Cp, int M, int N, int K, int c_f32) {
  __shared__ unsigned short As[128 * 64];   // 16 KB
  __shared__ unsigned short Bs[64 * 64];    // 8 KB
  int tid = threadIdx.x;
  int w = tid >> 6, l = tid & 63, g = l >> 4, lr = l & 15;
  int wr = w >> 1, wc = w & 1;
  int m0 = blockIdx.y * 128, n0 = blockIdx.x * 64;
  int sk = lr & 7;   // fragment-read swizzle key

  f32x4 acc[4][2] = {};

  for (int k0 = 0; k0 < K; k0 += 64) {
#pragma unroll
    for (int i = 0; i < 4; ++i) {
      int c = i * 256 + tid;             // 16B unit index, 8 units/row
      int row = c >> 3, srcu = ((c & 7) ^ (row & 7)) * 8;
      async16(A + (size_t)(m0 + row) * K + k0 + srcu, (char*)As + c * 16);
    }
#pragma unroll
    for (int i = 0; i < 2; ++i) {
      int c = i * 256 + tid;
      int row = c >> 3, srcu = ((c & 7) ^ (row & 7)) * 8;
      async16(Bt + (size_t)(n0 + row) * K + k0 + srcu, (char*)Bs + c * 16);
    }
    __syncthreads();

    s16x8 af[2][4], bfr[2][2];
#pragma unroll
    for (int ks = 0; ks < 2; ++ks) {
#pragma unroll
      for (int m = 0; m < 4; ++m)
        af[ks][m] = *(const s16x8*)(As + (wr * 64 + m * 16 + lr) * 64 +
                                    ((ks * 4 + g) ^ sk) * 8);
#pragma unroll
      for (int n = 0; n < 2; ++n)
        bfr[ks][n] = *(const s16x8*)(Bs + (wc * 32 + n * 16 + lr) * 64 +
                                     ((ks * 4 + g) ^ sk) * 8);
    }
#pragma unroll
    for (int ks = 0; ks < 2; ++ks)
#pragma unroll
      for (int m = 0; m < 4; ++m)
#pragma unroll
        for (int n = 0; n < 2; ++n)
          acc[m][n] = __builtin_amdgcn_mfma_f32_16x16x32_bf16(
              af[ks][m], bfr[ks][n], acc[m][n], 0, 0, 0);
    __syncthreads();
  }

  // C/D layout: row = (l>>4)*4 + r, col = l&15  [HW-verified]
  if (c_f32) {
    float* C = (float*)Cp;
#pragma unroll
    for (int m = 0; m < 4; ++m)
#pragma unroll
      for (int n = 0; n < 2; ++n)
#pragma unroll
        for (int r = 0; r < 4; ++r)
          C[(size_t)(m0 + wr * 64 + m * 16 + g * 4 + r) * N +
            n0 + wc * 32 + n * 16 + lr] = acc[m][n][r];
  } else {
    unsigned short* C = (unsigned short*)Cp;
#pragma unroll
    for (int m = 0; m < 4; ++m)
#pragma unroll
      for (int n = 0; n < 2; ++n)
#pragma unroll
        for (int r = 0; r < 4; ++r)
          C[(size_t)(m0 + wr * 64 + m * 16 + g * 4 + r) * N +
            n0 + wc * 32 + n * 16 + lr] = f2bf(acc[m][n][r]);
  }
}

// ---------------- flash attention (swapped QK^T, kv-split 8-wave) ----------------
// 512 blocks x 512 threads. Block n: pair (31-ip, ip), ip=n>>5; bh=n&31.
// Waves 0-3 (group 0): q-strips 0-3, kv tiles [0, ceil(nt/2));
// waves 4-7 (group 1): same q-strips, kv tiles [ceil(nt/2), nt).
// Per-group double-buffered K/V; per-pass (o,m,l) merge via LDS overlay.
// Swapped S^T = mfma(K,Q): lane (g,lr) holds S[q=qw+lr][kv=nf*16+g*4+r].
// Softmax in exp2 domain (LOG2E pre-folded into Q).
__global__ __launch_bounds__(512, 4) void attn_fused(
    const unsigned short* __restrict__ QKV, unsigned short* __restrict__ Y) {
  __shared__ char smem[81920];
  // 0:      K group0 (2 bufs x 8 KB) | 16384: K group1
  // 32768:  V group0 (2 bufs x 8 KB) | 49152: V group1
  // 65536:  P, 8 waves x 2 KB
  // merge overlay (post-loop): MO f32[16][256] @0 (16 KB), MM @16384, ML @17408

  const int T = 2048, CS = 1536;
  int tid = threadIdx.x;
  int w = tid >> 6, l = tid & 63, g = l >> 4, lr = l & 15;
  int grp = w >> 2, ws = w & 3, gt = tid & 255;
  int n = blockIdx.x;
  int ip = n >> 5;
  int bh = n & 31, b = bh >> 4, h = bh & 15, kvh = h >> 2;
  int sx = lr & 7;

  unsigned short* Kg = (unsigned short*)(smem + grp * 16384);
  unsigned short* Vg = (unsigned short*)(smem + 32768 + grp * 16384);
  unsigned short* Pw = (unsigned short*)(smem + 65536 + w * 2048);
  float* MO = (float*)(smem);
  float* MM = (float*)(smem + 16384);
  float* ML = (float*)(smem + 17408);

  const unsigned short* Qp = QKV + (size_t)b * T * CS + h * 64;
  const unsigned short* Kp = QKV + (size_t)b * T * CS + 1024 + kvh * 64;
  const unsigned short* Vp = QKV + (size_t)b * T * CS + 1280 + kvh * 64;

  int kvA = gt & 63, dA = (gt >> 6) * 8, dB = dA + 32;

  for (int pass = 0; pass < 2; ++pass) {
    int qt = pass ? ip : (31 - ip);
    int nt = qt + 1;
    int H1 = (nt + 1) >> 1;            // group 0 tile count; ITER
    int t0 = grp ? H1 : 0;
    int cnt = grp ? (nt - H1) : H1;
    int qw = qt * 64 + ws * 16;
    int q_mine = qw + lr;

    s16x8 qf[2];
#pragma unroll
    for (int ks = 0; ks < 2; ++ks)
      qf[ks] = *(const s16x8*)(Qp + (size_t)q_mine * CS + ks * 32 + g * 8);

    f32x4 o[4] = {};
    float mrun = -1e30f, lrun = 0.f;

    __syncthreads();   // prev-pass merge reads done before restaging K region

    // ---- prologue: stage my group's tile t0 into buf 0 ----
    if (cnt > 0) {
#pragma unroll
      for (int i = 0; i < 2; ++i) {
        int c = i * 256 + gt;
        int row = c >> 3, srcc = ((c & 7) ^ (row & 7)) * 8;
        async16(Kp + (size_t)(t0 * 64 + row) * CS + srcc, (char*)Kg + c * 16);
      }
#pragma unroll
      for (int i = 0; i < 2; ++i) {
        int c = i * 256 + gt;
        int kv = c & 63, d0v = (c >> 6) * 8;
        s16x8 vv = *(const s16x8*)(Vp + (size_t)(t0 * 64 + kv) * CS + d0v);
#pragma unroll
        for (int j = 0; j < 8; ++j)
          Vg[(d0v + j) * 64 + (kv ^ (j * 8))] = (unsigned short)vv[j];
      }
    }
    __syncthreads();

    int cur = 0;
    for (int j = 0; j < H1; ++j) {
      int tj = t0 + j;
      bool active = (j < cnt);
      bool hasnext = (j + 1 < cnt);
      int kv0 = tj * 64;

      // ---- stage next tile: K async->LDS(back), V ->regs ----
      s16x8 vvA, vvB;
      if (hasnext) {
        int kvn = kv0 + 64;
#pragma unroll
        for (int i = 0; i < 2; ++i) {
          int c = i * 256 + gt;
          int row = c >> 3, srcc = ((c & 7) ^ (row & 7)) * 8;
          async16(Kp + (size_t)(kvn + row) * CS + srcc,
                  (char*)Kg + (cur ^ 1) * 8192 + c * 16);
        }
        vvA = *(const s16x8*)(Vp + (size_t)(kvn + kvA) * CS + dA);
        vvB = *(const s16x8*)(Vp + (size_t)(kvn + kvA) * CS + dB);
      }

      if (active) {
        const unsigned short* Kc = Kg + cur * 4096;
        const unsigned short* Vc = Vg + cur * 4096;
        f32x4 s[4];
        __builtin_amdgcn_s_setprio(1);
#pragma unroll
        for (int nf = 0; nf < 4; ++nf) {
          f32x4 z = {};
#pragma unroll
          for (int ks = 0; ks < 2; ++ks) {
            s16x8 kf = *(const s16x8*)(Kc + (nf * 16 + lr) * 64 +
                                       ((ks * 4 + g) ^ sx) * 8);
            z = __builtin_amdgcn_mfma_f32_16x16x32_bf16(kf, qf[ks], z, 0, 0, 0);
          }
          s[nf] = z;
        }
        __builtin_amdgcn_s_setprio(0);

        if (tj == nt - 1) {   // diagonal tile: causal mask
#pragma unroll
          for (int nf = 0; nf < 4; ++nf)
#pragma unroll
            for (int r = 0; r < 4; ++r)
              if (kv0 + nf * 16 + g * 4 + r > q_mine) s[nf][r] = -1e30f;
        }

        // ---- softmax (exp2 domain): 16 in-lane + 2 shuffles ----
        float mt = s[0][0];
#pragma unroll
        for (int nf = 0; nf < 4; ++nf)
#pragma unroll
          for (int r = 0; r < 4; ++r) mt = fmaxf(mt, s[nf][r]);
        mt = fmaxf(mt, __shfl_xor(mt, 16, 64));
        mt = fmaxf(mt, __shfl_xor(mt, 32, 64));

        if (__any(mt > mrun + 11.5416f)) {   // defer-max (8 nat in exp2 units)
          float mnew = fmaxf(mrun, mt);
          float corr = exp2f(mrun - mnew);
          float psum = 0.f;
#pragma unroll
          for (int nf = 0; nf < 4; ++nf)
#pragma unroll
            for (int r = 0; r < 4; ++r) {
              float p = exp2f(s[nf][r] - mnew);
              s[nf][r] = p;
              psum += p;
            }
          psum += __shfl_xor(psum, 16, 64);
          psum += __shfl_xor(psum, 32, 64);
          lrun = lrun * corr + psum;
          mrun = mnew;
#pragma unroll
          for (int r = 0; r < 4; ++r) {
            float cr = __shfl(corr, g * 4 + r, 64);
#pragma unroll
            for (int d0 = 0; d0 < 4; ++d0) o[d0][r] *= cr;
          }
        } else {
          float psum = 0.f;
#pragma unroll
          for (int nf = 0; nf < 4; ++nf)
#pragma unroll
            for (int r = 0; r < 4; ++r) {
              float p = exp2f(s[nf][r] - mrun);
              s[nf][r] = p;
              psum += p;
            }
          psum += __shfl_xor(psum, 16, 64);
          psum += __shfl_xor(psum, 32, 64);
          lrun += psum;
        }

        // ---- P -> LDS via cvt_pk (b64 writes), then PV ----
#pragma unroll
        for (int nf = 0; nf < 4; ++nf) {
          uint2 pv;
          pv.x = cvtpk(s[nf][0], s[nf][1]);
          pv.y = cvtpk(s[nf][2], s[nf][3]);
          *(uint2*)(Pw + lr * 64 + ((nf * 16 + g * 4) ^ (sx * 8))) = pv;
        }
        asm volatile("s_waitcnt lgkmcnt(0)" ::: "memory");
        __builtin_amdgcn_sched_barrier(0);   // rule #18

        s16x8 pf[2];
#pragma unroll
        for (int ks = 0; ks < 2; ++ks)
          pf[ks] = *(const s16x8*)(Pw + lr * 64 + ((ks * 4 + g) ^ sx) * 8);
        __builtin_amdgcn_s_setprio(1);
#pragma unroll
        for (int d0 = 0; d0 < 4; ++d0)
#pragma unroll
          for (int ks = 0; ks < 2; ++ks) {
            s16x8 vf = *(const s16x8*)(Vc + (d0 * 16 + lr) * 64 +
                                       ((ks * 4 + g) ^ sx) * 8);
            o[d0] = __builtin_amdgcn_mfma_f32_16x16x32_bf16(pf[ks], vf, o[d0], 0, 0, 0);
          }
        __builtin_amdgcn_s_setprio(0);
      }

      // ---- write staged V regs -> back buffer ----
      if (hasnext) {
#pragma unroll
        for (int j2 = 0; j2 < 8; ++j2)
          Vg[cur == 0 ? 4096 + (dA + j2) * 64 + (kvA ^ (j2 * 8))
                      : (dA + j2) * 64 + (kvA ^ (j2 * 8))] = (unsigned short)vvA[j2];
#pragma unroll
        for (int j2 = 0; j2 < 8; ++j2)
          Vg[cur == 0 ? 4096 + (dB + j2) * 64 + (kvA ^ (j2 * 8))
                      : (dB + j2) * 64 + (kvA ^ (j2 * 8))] = (unsigned short)vvB[j2];
      }
      __syncthreads();   // drains vmcnt (K async) + lgkm (V writes)
      cur ^= 1;
    }

    // ---- merge group 1 -> group 0 (overlay on dead K region) ----
    int mbase = ws * 64 + l;
    if (grp == 1) {
#pragma unroll
      for (int d0 = 0; d0 < 4; ++d0)
#pragma unroll
        for (int r = 0; r < 4; ++r)
          MO[(d0 * 4 + r) * 256 + mbase] = o[d0][r];
      MM[mbase] = mrun;
      ML[mbase] = lrun;
    }
    __syncthreads();
    if (grp == 0) {
      float m1 = MM[mbase], l1 = ML[mbase];
      float mS = fmaxf(mrun, m1);
      float c0 = exp2f(mrun - mS), c1 = exp2f(m1 - mS);
      float lS = lrun * c0 + l1 * c1;
#pragma unroll
      for (int r = 0; r < 4; ++r) {
        float cr0 = __shfl(c0, g * 4 + r, 64);
        float cr1 = __shfl(c1, g * 4 + r, 64);
        float lv  = __shfl(lS, g * 4 + r, 64);
        float inv = 1.f / lv;
        size_t rowoff = (size_t)(b * T + qw + g * 4 + r) * 1024 + h * 64;
#pragma unroll
        for (int d0 = 0; d0 < 4; ++d0) {
          float om = o[d0][r] * cr0 + MO[(d0 * 4 + r) * 256 + mbase] * cr1;
          Y[rowoff + d0 * 16 + lr] = f2bf(om * inv);
        }
      }
    }
  }
}

// ---------------- launch ----------------

extern "C" void kernel_launch(void* const* d_in, const int* in_sizes, int n_in,
                              void* d_out, int out_size, void* d_ws, size_t ws_size,
                              hipStream_t stream) {
  const float* x    = (const float*)d_in[0];
  const float* cosb = (const float*)d_in[1];
  const float* sinb = (const float*)d_in[2];
  const float* Wq   = (const float*)d_in[3];
  const float* Wk   = (const float*)d_in[4];
  const float* Wv   = (const float*)d_in[5];
  const float* Wo   = (const float*)d_in[6];
  float* out = (float*)d_out;

  // Buffer map:
  //   d_out (16 MB): QKVb [4096][1536] bf16 = 12 MB  (dead at final gemm)
  //   d_ws: xb 0..8M | Wqkvt 8..11M | Wot 11..13M ; Yb aliases xb after attn
  char* ob = (char*)d_out;
  char* ws = (char*)d_ws;
  const size_t MB = 1024 * 1024;
  unsigned short* QKVb  = (unsigned short*)(ob);
  unsigned short* xb    = (unsigned short*)(ws);
  unsigned short* Wqkvt = (unsigned short*)(ws + 8 * MB);
  unsigned short* Wot   = (unsigned short*)(ws + 11 * MB);
  unsigned short* Yb    = xb;   // x-content dead after QKV gemm

  conv_f32_to_bf16<<<4096, 256, 0, stream>>>(x, xb, 4096 * 1024);
  // pack W_qkv^T rows: [0,1024) = Wq, [1024,1280) = Wk, [1280,1536) = Wv
  transpose_conv<<<dim3(32, 32), dim3(32, 8), 0, stream>>>(Wq, Wqkvt, 1024, 1024);
  transpose_conv<<<dim3(8, 32), dim3(32, 8), 0, stream>>>(Wk, Wqkvt + (size_t)1024 * 1024, 1024, 256);
  transpose_conv<<<dim3(8, 32), dim3(32, 8), 0, stream>>>(Wv, Wqkvt + (size_t)1280 * 1024, 1024, 256);
  transpose_conv<<<dim3(32, 32), dim3(32, 8), 0, stream>>>(Wo, Wot, 1024, 1024);

  // fused QKV projection: [4096][1536] bf16
  gemm_bt<<<dim3(24, 32), 256, 0, stream>>>(xb, Wqkvt, QKVb, 4096, 1536, 1024, 0);

  // RoPE on Q (x0.125*log2e) + K in one pass
  rope_qk<<<10240, 256, 0, stream>>>(QKVb, cosb, sinb);

  // attention -> Yb bf16 [B*T][1024]
  attn_fused<<<dim3(512), 512, 0, stream>>>(QKVb, Yb);

  // output projection (fp32, overwrites d_out)
  gemm_bt<<<dim3(16, 32), 256, 0, stream>>>(Yb, Wot, out, 4096, 1024, 1024, 1);
}

// Round 11
// 142.894 us; speedup vs baseline: 1.2437x; 1.2437x over previous
//
#include <hip/hip_runtime.h>
#include <hip/hip_bf16.h>

// Fused causal self-attention (GQA) for MI355X/gfx950.
// Shapes: B=2, T=2048, C=1024, H=16, Hkv=4, D=64.
// Round 11: revert R10 (spill-bound). Attn rewritten on mfma_32x32x16:
// 2 waves x 32 q/block, 1024 blocks heavy-first; swapped QK^T -> lane-local
// softmax rows; in-register P fragments (cvt_pk + shfl_xor32, no P LDS);
// b64 V-transpose staging; double-buffered K/V (T14). GEMMs = R9 (proven).

typedef __attribute__((ext_vector_type(8))) short s16x8;    // 8 x bf16 raw
typedef __attribute__((ext_vector_type(16))) float f32x16;  // 32x32 C/D
typedef __attribute__((ext_vector_type(4))) float f32x4;
typedef __attribute__((ext_vector_type(4))) unsigned short u16x4;
typedef __attribute__((ext_vector_type(4))) unsigned int u32x4;

#define LOG2E 1.44269504088896340736f

__device__ __forceinline__ float bf2f(unsigned short u) {
  unsigned int i = ((unsigned int)u) << 16;
  return __builtin_bit_cast(float, i);
}
__device__ __forceinline__ unsigned short f2bf(float f) {
  unsigned int i = __builtin_bit_cast(unsigned int, f);
  i += 0x7fffu + ((i >> 16) & 1u);   // RNE
  return (unsigned short)(i >> 16);
}
__device__ __forceinline__ unsigned int cvtpk(float lo, float hi) {
  unsigned int r;                    // low half <- lo, high half <- hi
  asm("v_cvt_pk_bf16_f32 %0, %1, %2" : "=v"(r) : "v"(lo), "v"(hi));
  return r;
}

__device__ __forceinline__ void async16(const void* g, void* l) {
  __builtin_amdgcn_global_load_lds(
      (const __attribute__((address_space(1))) void*)g,
      (__attribute__((address_space(3))) void*)l, 16, 0, 0);
}

// ---------------- prep kernels ----------------

__global__ void conv_f32_to_bf16(const float* __restrict__ in,
                                 unsigned short* __restrict__ out, int n) {
  int i = (blockIdx.x * blockDim.x + threadIdx.x) * 4;
  if (i + 3 < n) {
    float4 v = *(const float4*)(in + i);
    u16x4 o = { f2bf(v.x), f2bf(v.y), f2bf(v.z), f2bf(v.w) };
    *(u16x4*)(out + i) = o;
  }
}

// W [K][N] fp32 -> Wt [N][K] bf16
__global__ void transpose_conv(const float* __restrict__ W,
                               unsigned short* __restrict__ Wt, int K, int N) {
  __shared__ float tile[32][33];
  int n0 = blockIdx.x * 32, k0 = blockIdx.y * 32;
  int tx = threadIdx.x, ty = threadIdx.y;
  for (int i = ty; i < 32; i += 8)
    tile[i][tx] = W[(size_t)(k0 + i) * N + n0 + tx];
  __syncthreads();
  for (int i = ty; i < 32; i += 8)
    Wt[(size_t)(n0 + i) * K + k0 + tx] = f2bf(tile[tx][i]);
}

// RoPE on packed QKV [4096][1536]: heads 0..15 = Q (scaled 0.125*log2e ->
// softmax in exp2 domain), heads 16..19 = K at col offset 1024.
__global__ void rope_qk(unsigned short* __restrict__ QKV,
                        const float* __restrict__ cosb,
                        const float* __restrict__ sinb) {
  int idx = blockIdx.x * blockDim.x + threadIdx.x;
  int d = idx & 31;
  int hh = (idx >> 5) % 20;
  int row = idx / (32 * 20);
  int t = row & 2047;
  size_t base;
  float mul;
  if (hh < 16) { base = (size_t)row * 1536 + hh * 64 + d;   mul = 0.125f * LOG2E; }
  else         { base = (size_t)row * 1536 + 1024 + (hh - 16) * 64 + d; mul = 1.0f; }
  float x1 = bf2f(QKV[base]), x2 = bf2f(QKV[base + 32]);
  float c = cosb[t * 32 + d], s = sinb[t * 32 + d];
  QKV[base]      = f2bf((x1 * c + x2 * s) * mul);
  QKV[base + 32] = f2bf((-x1 * s + x2 * c) * mul);
}

// ---------------- GEMM: C[M,N] = A[M,K] * Bt[N,K]^T ----------------
// 128x64 tile, BK=64, 4 waves (2x2), wave = 64x32 via 4x2x2 16x16x32 MFMA.
__global__ __launch_bounds__(256) void gemm_bt(
    const unsigned short* __restrict__ A, const unsigned short* __restrict__ Bt,
    void* __restrict__ Cp, int M, int N, int K, int c_f32) {
  __shared__ unsigned short As[128 * 64];   // 16 KB
  __shared__ unsigned short Bs[64 * 64];    // 8 KB
  int tid = threadIdx.x;
  int w = tid >> 6, l = tid & 63, g = l >> 4, lr = l & 15;
  int wr = w >> 1, wc = w & 1;
  int m0 = blockIdx.y * 128, n0 = blockIdx.x * 64;
  int sk = lr & 7;   // fragment-read swizzle key

  f32x4 acc[4][2] = {};

  for (int k0 = 0; k0 < K; k0 += 64) {
#pragma unroll
    for (int i = 0; i < 4; ++i) {
      int c = i * 256 + tid;             // 16B unit index, 8 units/row
      int row = c >> 3, srcu = ((c & 7) ^ (row & 7)) * 8;
      async16(A + (size_t)(m0 + row) * K + k0 + srcu, (char*)As + c * 16);
    }
#pragma unroll
    for (int i = 0; i < 2; ++i) {
      int c = i * 256 + tid;
      int row = c >> 3, srcu = ((c & 7) ^ (row & 7)) * 8;
      async16(Bt + (size_t)(n0 + row) * K + k0 + srcu, (char*)Bs + c * 16);
    }
    __syncthreads();

    s16x8 af[2][4], bfr[2][2];
#pragma unroll
    for (int ks = 0; ks < 2; ++ks) {
#pragma unroll
      for (int m = 0; m < 4; ++m)
        af[ks][m] = *(const s16x8*)(As + (wr * 64 + m * 16 + lr) * 64 +
                                    ((ks * 4 + g) ^ sk) * 8);
#pragma unroll
      for (int n = 0; n < 2; ++n)
        bfr[ks][n] = *(const s16x8*)(Bs + (wc * 32 + n * 16 + lr) * 64 +
                                     ((ks * 4 + g) ^ sk) * 8);
    }
#pragma unroll
    for (int ks = 0; ks < 2; ++ks)
#pragma unroll
      for (int m = 0; m < 4; ++m)
#pragma unroll
        for (int n = 0; n < 2; ++n)
          acc[m][n] = __builtin_amdgcn_mfma_f32_16x16x32_bf16(
              af[ks][m], bfr[ks][n], acc[m][n], 0, 0, 0);
    __syncthreads();
  }

  // C/D layout: row = (l>>4)*4 + r, col = l&15  [HW-verified]
  if (c_f32) {
    float* C = (float*)Cp;
#pragma unroll
    for (int m = 0; m < 4; ++m)
#pragma unroll
      for (int n = 0; n < 2; ++n)
#pragma unroll
        for (int r = 0; r < 4; ++r)
          C[(size_t)(m0 + wr * 64 + m * 16 + g * 4 + r) * N +
            n0 + wc * 32 + n * 16 + lr] = acc[m][n][r];
  } else {
    unsigned short* C = (unsigned short*)Cp;
#pragma unroll
    for (int m = 0; m < 4; ++m)
#pragma unroll
      for (int n = 0; n < 2; ++n)
#pragma unroll
        for (int r = 0; r < 4; ++r)
          C[(size_t)(m0 + wr * 64 + m * 16 + g * 4 + r) * N +
            n0 + wc * 32 + n * 16 + lr] = f2bf(acc[m][n][r]);
  }
}

// ---------------- flash attention (32x32 MFMA, swapped QK^T) ----------------
// 1024 blocks x 128 threads (2 waves x 32 q-rows), heavy-first qt=31-(n>>5).
// KVBLK=64 double-buffered. S^T = mfma32(K,Q): lane holds the FULL 32-score
// row for q = qw + (l&31); kv = kb*32 + (r&3)+8*(r>>2)+4*(l>>5).
// P fragments built in-register (cvt_pk + shfl_xor 32). O^T = mfma32(V^T, P^T).
__global__ __launch_bounds__(128) void attn_fused(
    const unsigned short* __restrict__ QKV, unsigned short* __restrict__ Y) {
  __shared__ unsigned short Kt[2][64 * 64];   // [kv][d], swizzled (16 KB)
  __shared__ unsigned short Vt[2][64 * 64];   // [d][kv], swizzled (16 KB)

  const int T = 2048, CS = 1536;
  int tid = threadIdx.x;
  int wv = tid >> 6, l = tid & 63;
  int lq = l & 31, hi = l >> 5;
  int n = blockIdx.x;
  int qt = 31 - (n >> 5);              // heavy blocks first
  int bh = n & 31, b = bh >> 4, h = bh & 15, kvh = h >> 2;
  int sx = l & 7;                      // row-swizzle key (lq&7)
  int qw = qt * 64 + wv * 32;
  int q_mine = qw + lq;

  const unsigned short* Qp = QKV + (size_t)b * T * CS + h * 64;
  const unsigned short* Kp = QKV + (size_t)b * T * CS + 1024 + kvh * 64;
  const unsigned short* Vp = QKV + (size_t)b * T * CS + 1280 + kvh * 64;

  // Q B-fragments: col q = lq, k-elems d = ks*16 + hi*8 + 0..7
  s16x8 qf[4];
#pragma unroll
  for (int ks = 0; ks < 4; ++ks)
    qf[ks] = *(const s16x8*)(Qp + (size_t)q_mine * CS + ks * 16 + hi * 8);

  f32x16 o0 = {}, o1 = {};             // O^T: rows d (db*32+...), col q=lq
  float mrun = -1e30f, lrun = 0.f;     // per-lane (q-local)

  int ntiles = qt + 1;
  // V staging decode: thread covers kv 4-pack x 8 d
  int kvi = (tid & 15) * 4, dc = (tid >> 4) * 8;

  // ---- prologue: stage tile 0 into buffer 0 ----
#pragma unroll
  for (int i = 0; i < 4; ++i) {
    int c = i * 128 + tid;
    int row = c >> 3, srcu = ((c & 7) ^ (row & 7)) * 8;
    async16(Kp + (size_t)row * CS + srcu, (char*)(&Kt[0][0]) + c * 16);
  }
  {
    s16x8 v0 = *(const s16x8*)(Vp + (size_t)(kvi + 0) * CS + dc);
    s16x8 v1 = *(const s16x8*)(Vp + (size_t)(kvi + 1) * CS + dc);
    s16x8 v2 = *(const s16x8*)(Vp + (size_t)(kvi + 2) * CS + dc);
    s16x8 v3 = *(const s16x8*)(Vp + (size_t)(kvi + 3) * CS + dc);
#pragma unroll
    for (int j = 0; j < 8; ++j) {
      u16x4 pk = { (unsigned short)v0[j], (unsigned short)v1[j],
                   (unsigned short)v2[j], (unsigned short)v3[j] };
      *(u16x4*)(&Vt[0][0] + (dc + j) * 64 + (kvi ^ (j * 8))) = pk;
    }
  }
  __syncthreads();

  int cur = 0;
  for (int it = 0; it < ntiles; ++it) {
    int kv0 = it * 64;
    bool hasnext = (it + 1 < ntiles);

    // ---- T14 stage next tile: K async->LDS(back), V->regs (write later) ----
    s16x8 v0, v1, v2, v3;
    if (hasnext) {
      int kvn = kv0 + 64;
#pragma unroll
      for (int i = 0; i < 4; ++i) {
        int c = i * 128 + tid;
        int row = c >> 3, srcu = ((c & 7) ^ (row & 7)) * 8;
        async16(Kp + (size_t)(kvn + row) * CS + srcu,
                (char*)(&Kt[cur ^ 1][0]) + c * 16);
      }
      v0 = *(const s16x8*)(Vp + (size_t)(kvn + kvi + 0) * CS + dc);
      v1 = *(const s16x8*)(Vp + (size_t)(kvn + kvi + 1) * CS + dc);
      v2 = *(const s16x8*)(Vp + (size_t)(kvn + kvi + 2) * CS + dc);
      v3 = *(const s16x8*)(Vp + (size_t)(kvn + kvi + 3) * CS + dc);
    }

    const unsigned short* Kc = &Kt[cur][0];
    const unsigned short* Vc = &Vt[cur][0];

    // ---- S^T = K Q^T (8 mfma 32x32x16) ----
    f32x16 s0 = {}, s1 = {};
    __builtin_amdgcn_s_setprio(1);
#pragma unroll
    for (int ks = 0; ks < 4; ++ks) {
      int u = ((ks * 2 + hi) ^ sx) * 8;
      s16x8 kf0 = *(const s16x8*)(Kc + lq * 64 + u);
      s16x8 kf1 = *(const s16x8*)(Kc + (32 + lq) * 64 + u);
      s0 = __builtin_amdgcn_mfma_f32_32x32x16_bf16(kf0, qf[ks], s0, 0, 0, 0);
      s1 = __builtin_amdgcn_mfma_f32_32x32x16_bf16(kf1, qf[ks], s1, 0, 0, 0);
    }
    __builtin_amdgcn_s_setprio(0);

    if (it == ntiles - 1) {   // diagonal tile: causal mask
#pragma unroll
      for (int r = 0; r < 16; ++r) {
        int kvg = kv0 + (r & 3) + 8 * (r >> 2) + 4 * hi;
        if (kvg > q_mine) s0[r] = -1e30f;
        if (kvg + 32 > q_mine) s1[r] = -1e30f;
      }
    }

    // ---- softmax (exp2 domain): 31 in-lane fmax + 1 shfl ----
    float mt = s0[0];
#pragma unroll
    for (int r = 1; r < 16; ++r) mt = fmaxf(mt, s0[r]);
#pragma unroll
    for (int r = 0; r < 16; ++r) mt = fmaxf(mt, s1[r]);
    mt = fmaxf(mt, __shfl_xor(mt, 32, 64));

    if (__any(mt > mrun + 11.5416f)) {   // defer-max (8 nats in exp2 units)
      float mnew = fmaxf(mrun, mt);
      float corr = exp2f(mrun - mnew);
      float psum = 0.f;
#pragma unroll
      for (int r = 0; r < 16; ++r) {
        float p0 = exp2f(s0[r] - mnew); s0[r] = p0; psum += p0;
        float p1 = exp2f(s1[r] - mnew); s1[r] = p1; psum += p1;
      }
      psum += __shfl_xor(psum, 32, 64);
      lrun = lrun * corr + psum;
      mrun = mnew;
#pragma unroll
      for (int r = 0; r < 16; ++r) { o0[r] *= corr; o1[r] *= corr; }
    } else {
      float psum = 0.f;
#pragma unroll
      for (int r = 0; r < 16; ++r) {
        float p0 = exp2f(s0[r] - mrun); s0[r] = p0; psum += p0;
        float p1 = exp2f(s1[r] - mrun); s1[r] = p1; psum += p1;
      }
      psum += __shfl_xor(psum, 32, 64);
      lrun += psum;
    }

    // ---- in-register P fragments + PV (8 mfma 32x32x16) ----
    __builtin_amdgcn_s_setprio(1);
#pragma unroll
    for (int ks = 0; ks < 4; ++ks) {
      int rb = (ks & 1) * 8;
      const f32x16& sp = (ks < 2) ? s0 : s1;   // kb = ks>>1 (unrolled-const)
      unsigned int X0 = cvtpk(sp[rb + 0], sp[rb + 1]);
      unsigned int X1 = cvtpk(sp[rb + 2], sp[rb + 3]);
      unsigned int Y0 = cvtpk(sp[rb + 4], sp[rb + 5]);
      unsigned int Y1 = cvtpk(sp[rb + 6], sp[rb + 7]);
      unsigned int Z0 = hi ? X0 : Y0;
      unsigned int Z1 = hi ? X1 : Y1;
      unsigned int Zp0 = (unsigned int)__shfl_xor((int)Z0, 32, 64);
      unsigned int Zp1 = (unsigned int)__shfl_xor((int)Z1, 32, 64);
      u32x4 pw = { hi ? Zp0 : X0, hi ? Zp1 : X1,
                   hi ? Y0 : Zp0, hi ? Y1 : Zp1 };
      s16x8 pf = __builtin_bit_cast(s16x8, pw);
      int u = ((ks * 2 + hi) ^ sx) * 8;
      s16x8 vf0 = *(const s16x8*)(Vc + lq * 64 + u);
      s16x8 vf1 = *(const s16x8*)(Vc + (32 + lq) * 64 + u);
      o0 = __builtin_amdgcn_mfma_f32_32x32x16_bf16(vf0, pf, o0, 0, 0, 0);
      o1 = __builtin_amdgcn_mfma_f32_32x32x16_bf16(vf1, pf, o1, 0, 0, 0);
    }
    __builtin_amdgcn_s_setprio(0);

    // ---- write staged V regs -> back buffer (b64 packs) ----
    if (hasnext) {
      unsigned short* Vn = &Vt[cur ^ 1][0];
#pragma unroll
      for (int j = 0; j < 8; ++j) {
        u16x4 pk = { (unsigned short)v0[j], (unsigned short)v1[j],
                     (unsigned short)v2[j], (unsigned short)v3[j] };
        *(u16x4*)(Vn + (dc + j) * 64 + (kvi ^ (j * 8))) = pk;
      }
    }
    __syncthreads();   // drains vmcnt (K async) + lgkm (V writes)
    cur ^= 1;
  }

  // ---- epilogue: per-lane q-local normalize; d = db*32+(r&3)+8(r>>2)+4hi ----
  float inv = 1.f / lrun;
  size_t rowoff = (size_t)(b * T + q_mine) * 1024 + h * 64;
#pragma unroll
  for (int rr = 0; rr < 4; ++rr) {
    int d0 = rr * 8 + 4 * hi;
    u16x4 w0 = { f2bf(o0[rr * 4 + 0] * inv), f2bf(o0[rr * 4 + 1] * inv),
                 f2bf(o0[rr * 4 + 2] * inv), f2bf(o0[rr * 4 + 3] * inv) };
    *(u16x4*)(Y + rowoff + d0) = w0;
    u16x4 w1 = { f2bf(o1[rr * 4 + 0] * inv), f2bf(o1[rr * 4 + 1] * inv),
                 f2bf(o1[rr * 4 + 2] * inv), f2bf(o1[rr * 4 + 3] * inv) };
    *(u16x4*)(Y + rowoff + 32 + d0) = w1;
  }
}

// ---------------- launch ----------------

extern "C" void kernel_launch(void* const* d_in, const int* in_sizes, int n_in,
                              void* d_out, int out_size, void* d_ws, size_t ws_size,
                              hipStream_t stream) {
  const float* x    = (const float*)d_in[0];
  const float* cosb = (const float*)d_in[1];
  const float* sinb = (const float*)d_in[2];
  const float* Wq   = (const float*)d_in[3];
  const float* Wk   = (const float*)d_in[4];
  const float* Wv   = (const float*)d_in[5];
  const float* Wo   = (const float*)d_in[6];
  float* out = (float*)d_out;

  // Buffer map:
  //   d_out (16 MB): QKVb [4096][1536] bf16 = 12 MB  (dead at final gemm)
  //   d_ws: xb 0..8M | Wqkvt 8..11M | Wot 11..13M ; Yb aliases xb after attn
  char* ob = (char*)d_out;
  char* ws = (char*)d_ws;
  const size_t MB = 1024 * 1024;
  unsigned short* QKVb  = (unsigned short*)(ob);
  unsigned short* xb    = (unsigned short*)(ws);
  unsigned short* Wqkvt = (unsigned short*)(ws + 8 * MB);
  unsigned short* Wot   = (unsigned short*)(ws + 11 * MB);
  unsigned short* Yb    = xb;   // x-content dead after QKV gemm

  conv_f32_to_bf16<<<4096, 256, 0, stream>>>(x, xb, 4096 * 1024);
  // pack W_qkv^T rows: [0,1024) = Wq, [1024,1280) = Wk, [1280,1536) = Wv
  transpose_conv<<<dim3(32, 32), dim3(32, 8), 0, stream>>>(Wq, Wqkvt, 1024, 1024);
  transpose_conv<<<dim3(8, 32), dim3(32, 8), 0, stream>>>(Wk, Wqkvt + (size_t)1024 * 1024, 1024, 256);
  transpose_conv<<<dim3(8, 32), dim3(32, 8), 0, stream>>>(Wv, Wqkvt + (size_t)1280 * 1024, 1024, 256);
  transpose_conv<<<dim3(32, 32), dim3(32, 8), 0, stream>>>(Wo, Wot, 1024, 1024);

  // fused QKV projection: [4096][1536] bf16
  gemm_bt<<<dim3(24, 32), 256, 0, stream>>>(xb, Wqkvt, QKVb, 4096, 1536, 1024, 0);

  // RoPE on Q (x0.125*log2e) + K in one pass
  rope_qk<<<10240, 256, 0, stream>>>(QKVb, cosb, sinb);

  // attention -> Yb bf16 [B*T][1024]
  attn_fused<<<dim3(1024), 128, 0, stream>>>(QKVb, Yb);

  // output projection (fp32, overwrites d_out)
  gemm_bt<<<dim3(16, 32), 256, 0, stream>>>(Yb, Wot, out, 4096, 1024, 1024, 1);
}